// Round 13
// baseline (14.317 us; speedup 1.0000x reference)
//
#include <hip/hip_runtime.h>
#include <hip/hip_fp16.h>
#include <math.h>

#define NPART 4096
#define HID 64
#define HI 8
#define PPB 8                   // particles per block
#define WPB 16                  // waves per block (2 waves per particle)
#define BLOCK (WPB * 64)        // 1024 threads
#define NUNIT (NPART / 4)       // 1024 scan units of 4 particles
#define HUNIT (NUNIT / 2)       // 512 units per half-range
#define CAP 144                 // per-wave flagged-unit list (half-range lambda~26, max~100)
#define TBL 256                 // dU(r) table, r in [0, 0.5]
#define TSCALE ((float)(TBL - 1) / 0.5f)
#define SCAN_THR 0.26f          // covers f16 rounding; process rechecks exact f32

struct alignas(8) H2x2 { __half2 a, b; };   // 4 f16 values (one unit, one coord)

__global__ __launch_bounds__(BLOCK, 8) void odefunc_kernel(
    const float* __restrict__ t_in,
    const float* __restrict__ z,
    const float* __restrict__ lnw,
    const float* __restrict__ W1,
    const float* __restrict__ b1,
    const float* __restrict__ Wv,
    const float* __restrict__ bv,
    const float* __restrict__ Wg,
    const float* __restrict__ bg,
    const float* __restrict__ Wi1,
    const float* __restrict__ bi1,
    const float* __restrict__ Wi2,
    const float* __restrict__ bi2,
    float* __restrict__ out)
{
    __shared__ H2x2 sX2[NUNIT];                 // 8 KB
    __shared__ H2x2 sY2[NUNIT];                 // 8 KB
    __shared__ H2x2 sZ2[NUNIT];                 // 8 KB
    __shared__ float sT[TBL];                   // 1 KB
    __shared__ unsigned short lists[WPB][CAP];  // 4.5 KB
    __shared__ float pf[PPB][3];                // half-1 partial forces

    const int tid = threadIdx.x;

    // ---- prologue: one unit (4 particles) per thread -> f16 SoA; dU table ----
    {
        const float4* z4 = (const float4*)z;
        const float4 r0 = z4[3 * tid + 0];
        const float4 r1 = z4[3 * tid + 1];
        const float4 r2 = z4[3 * tid + 2];
        H2x2 hx, hy, hz;
        hx.a = __floats2half2_rn(r0.x, r0.w);
        hx.b = __floats2half2_rn(r1.z, r2.y);
        hy.a = __floats2half2_rn(r0.y, r1.x);
        hy.b = __floats2half2_rn(r1.w, r2.z);
        hz.a = __floats2half2_rn(r0.z, r1.y);
        hz.b = __floats2half2_rn(r2.x, r2.w);
        sX2[tid] = hx;
        sY2[tid] = hy;
        sZ2[tid] = hz;

        if (tid < TBL) {
            const float r = (float)tid * (0.5f / (float)(TBL - 1));
            float acc = 0.f;
            #pragma unroll
            for (int kk = 0; kk < HI; ++kk) {
                const float s = __expf(-2.0f * fmaf(r, Wi1[kk], bi1[kk]));
                const float den = 1.0f + s;
                acc += 4.0f * Wi1[kk] * Wi2[kk] * s *
                       __builtin_amdgcn_rcpf(den * den);
            }
            sT[tid] = acc;
        }
    }
    __syncthreads();

    const int lane = tid & 63;
    const int wid  = tid >> 6;
    const int pidx = wid & (PPB - 1);
    const int half = wid >> 3;
    const int i    = blockIdx.x * PPB + pidx;

    const float zix = z[3 * i + 0];
    const float ziy = z[3 * i + 1];
    const float ziz = z[3 * i + 2];

    // ---- f_net MLP on half-0 waves only (cheap tanh) ----
    float v0 = 0.f, v1 = 0.f, v2 = 0.f, grow = 0.f;
    if (half == 0) {
        const float tval = t_in[0];
        float pre = zix * W1[0 * HID + lane]
                  + ziy * W1[1 * HID + lane]
                  + ziz * W1[2 * HID + lane]
                  + tval * W1[3 * HID + lane]
                  + b1[lane];
        const float e2 = __expf(2.0f * pre);
        const float h = 1.0f - 2.0f * __builtin_amdgcn_rcpf(e2 + 1.0f);
        float pv0 = h * Wv[lane * 3 + 0];
        float pv1 = h * Wv[lane * 3 + 1];
        float pv2 = h * Wv[lane * 3 + 2];
        float pg  = h * Wg[lane];
        #pragma unroll
        for (int s = 1; s < 64; s <<= 1) {
            pv0 += __shfl_xor(pv0, s);
            pv1 += __shfl_xor(pv1, s);
            pv2 += __shfl_xor(pv2, s);
            pg  += __shfl_xor(pg, s);
        }
        v0 = pv0 + bv[0];
        v1 = pv1 + bv[1];
        v2 = pv2 + bv[2];
        grow = pg + bg[0];
    }

    unsigned short* myl = lists[wid];
    int cnt = 0;

    // ---- phase 1: f16 packed scan of this wave's half, one ballot/unit ----
    {
        const __half2 hxi = __float2half2_rn(zix);
        const __half2 hyi = __float2half2_rn(ziy);
        const __half2 hzi = __float2half2_rn(ziz);
        const int ubase = half * HUNIT;
        #pragma unroll 2
        for (int tt = 0; tt < HUNIT / 64; ++tt) {        // 8 iters
            const int u = ubase + tt * 64 + lane;
            const H2x2 xs = sX2[u];
            const H2x2 ys = sY2[u];
            const H2x2 zs = sZ2[u];
            const __half2 dxa = __hsub2(hxi, xs.a);
            const __half2 dya = __hsub2(hyi, ys.a);
            const __half2 dza = __hsub2(hzi, zs.a);
            const __half2 dxb = __hsub2(hxi, xs.b);
            const __half2 dyb = __hsub2(hyi, ys.b);
            const __half2 dzb = __hsub2(hzi, zs.b);
            const __half2 d2a = __hfma2(dxa, dxa, __hfma2(dya, dya, __hmul2(dza, dza)));
            const __half2 d2b = __hfma2(dxb, dxb, __hfma2(dyb, dyb, __hmul2(dzb, dzb)));
            const float m0 = __low2float(d2a), m1 = __high2float(d2a);
            const float m2 = __low2float(d2b), m3 = __high2float(d2b);
            const float m = fminf(fminf(m0, m1), fminf(m2, m3));
            const bool pred = (m < SCAN_THR);
            const unsigned long long bal = __ballot(pred);
            const unsigned int lo = (unsigned int)bal, hi = (unsigned int)(bal >> 32);
            const int pre = __builtin_amdgcn_mbcnt_hi(hi, __builtin_amdgcn_mbcnt_lo(lo, 0u));
            if (pred) myl[cnt + pre] = (unsigned short)u;
            cnt += __popcll(bal);
        }
    }

    // ---- phase 2: process flagged units; exact f32 from global (L2), table dU ----
    float fx = 0.f, fy = 0.f, fz = 0.f;
    {
        const float4* z4 = (const float4*)z;
        const float4* l4 = (const float4*)lnw;
        for (int base = 0; base < cnt; base += 64) {
            const int k = base + lane;
            const bool valid = (k < cnt);
            const int e = valid ? (int)myl[k] : 0;
            const float4 r0 = z4[3 * e + 0];
            const float4 r1 = z4[3 * e + 1];
            const float4 r2 = z4[3 * e + 2];
            const float4 lw = l4[e];
            #pragma unroll
            for (int q = 0; q < 4; ++q) {
                const int j = 4 * e + q;
                const float xj = (q == 0) ? r0.x : (q == 1) ? r0.w : (q == 2) ? r1.z : r2.y;
                const float yj = (q == 0) ? r0.y : (q == 1) ? r1.x : (q == 2) ? r1.w : r2.z;
                const float zj = (q == 0) ? r0.z : (q == 1) ? r1.y : (q == 2) ? r2.x : r2.w;
                const float lj = (q == 0) ? lw.x : (q == 1) ? lw.y : (q == 2) ? lw.z : lw.w;
                const float dx = zix - xj;
                const float dy = ziy - yj;
                const float dz = ziz - zj;
                const float d2 = dx * dx + dy * dy + dz * dz + 1e-8f;
                const float r = __builtin_amdgcn_sqrtf(d2);
                const bool ok = valid && (r < 0.5f) && (j != i);
                const float u = r * TSCALE;
                int i0 = (int)u;
                i0 = i0 > (TBL - 2) ? (TBL - 2) : i0;
                const float fr = u - (float)i0;
                const float t0 = sT[i0], t1 = sT[i0 + 1];
                const float dU = fmaf(fr, t1 - t0, t0);
                const float wj = __expf(lj);
                const float coeff = ok
                    ? (-0.0625f) * wj * dU * __builtin_amdgcn_rcpf(r) : 0.0f;
                fx = fmaf(coeff, dx, fx);
                fy = fmaf(coeff, dy, fy);
                fz = fmaf(coeff, dz, fz);
            }
        }
    }

    #pragma unroll
    for (int s = 1; s < 64; s <<= 1) {
        fx += __shfl_xor(fx, s);
        fy += __shfl_xor(fy, s);
        fz += __shfl_xor(fz, s);
    }

    if (half == 1 && lane == 0) {
        pf[pidx][0] = fx;
        pf[pidx][1] = fy;
        pf[pidx][2] = fz;
    }
    __syncthreads();

    if (half == 0 && lane == 0) {
        out[i * 3 + 0] = v0 + fx + pf[pidx][0];
        out[i * 3 + 1] = v1 + fy + pf[pidx][1];
        out[i * 3 + 2] = v2 + fz + pf[pidx][2];
        out[NPART * 3 + i] = grow;                         // dlnw_dt
        const float wi = __expf(lnw[i]);
        out[NPART * 3 + NPART + i] =
            (v0 * v0 + v1 * v1 + v2 * v2 + grow * grow) * wi;  // dm_dt
    }
}

extern "C" void kernel_launch(void* const* d_in, const int* in_sizes, int n_in,
                              void* d_out, int out_size, void* d_ws, size_t ws_size,
                              hipStream_t stream) {
    const float* t_in = (const float*)d_in[0];
    const float* z    = (const float*)d_in[1];
    const float* lnw  = (const float*)d_in[2];
    const float* W1   = (const float*)d_in[3];
    const float* b1   = (const float*)d_in[4];
    const float* Wv   = (const float*)d_in[5];
    const float* bv   = (const float*)d_in[6];
    const float* Wg   = (const float*)d_in[7];
    const float* bg   = (const float*)d_in[8];
    const float* Wi1  = (const float*)d_in[9];
    const float* bi1  = (const float*)d_in[10];
    const float* Wi2  = (const float*)d_in[11];
    const float* bi2  = (const float*)d_in[12];
    (void)bi2;
    float* out = (float*)d_out;

    odefunc_kernel<<<dim3(NPART / PPB), dim3(BLOCK), 0, stream>>>(
        t_in, z, lnw, W1, b1, Wv, bv, Wg, bg, Wi1, bi1, Wi2, bi2, out);
}

// Round 14
// 13.425 us; speedup vs baseline: 1.0664x; 1.0664x over previous
//
#include <hip/hip_runtime.h>
#include <hip/hip_fp16.h>
#include <math.h>

#define NPART 4096
#define HID 64
#define HI 8
#define IPB 16                  // particles per block = waves per block
#define BLOCK (IPB * 64)        // 1024 threads
#define NUNIT (NPART / 4)       // 1024 scan units of 4 particles
#define CAP 256                 // per-wave flagged-unit list (lambda~52, max~130)
#define TBL 256                 // dU(r) table, r in [0, 0.5]
#define TSCALE ((float)(TBL - 1) / 0.5f)
#define SCAN_THR 0.26f          // covers f16 rounding; process rechecks exact f32

struct alignas(16) H2x4 { __half2 xa, xb, ya, yb; };  // x,y of one 4-particle unit (b128)
struct alignas(8)  H2x2 { __half2 a, b; };            // z of one unit (b64)

__global__ __launch_bounds__(BLOCK) void odefunc_kernel(
    const float* __restrict__ t_in,
    const float* __restrict__ z,
    const float* __restrict__ lnw,
    const float* __restrict__ W1,
    const float* __restrict__ b1,
    const float* __restrict__ Wv,
    const float* __restrict__ bv,
    const float* __restrict__ Wg,
    const float* __restrict__ bg,
    const float* __restrict__ Wi1,
    const float* __restrict__ bi1,
    const float* __restrict__ Wi2,
    const float* __restrict__ bi2,
    float* __restrict__ out)
{
    __shared__ H2x4 sXY[NUNIT];                 // 16 KB
    __shared__ H2x2 sZ2[NUNIT];                 //  8 KB
    __shared__ float sT[TBL];                   //  1 KB
    __shared__ unsigned short lists[IPB][CAP];  //  8 KB

    const int tid = threadIdx.x;

    // ---- prologue: one unit (4 particles) per thread -> f16 SoA; dU table ----
    {
        const float4* z4 = (const float4*)z;
        const float4 r0 = z4[3 * tid + 0];
        const float4 r1 = z4[3 * tid + 1];
        const float4 r2 = z4[3 * tid + 2];
        // particle q of unit tid: q0=(r0.x,r0.y,r0.z) q1=(r0.w,r1.x,r1.y)
        //                         q2=(r1.z,r1.w,r2.x) q3=(r2.y,r2.z,r2.w)
        H2x4 hxy;
        hxy.xa = __floats2half2_rn(r0.x, r0.w);
        hxy.xb = __floats2half2_rn(r1.z, r2.y);
        hxy.ya = __floats2half2_rn(r0.y, r1.x);
        hxy.yb = __floats2half2_rn(r1.w, r2.z);
        H2x2 hz;
        hz.a = __floats2half2_rn(r0.z, r1.y);
        hz.b = __floats2half2_rn(r2.x, r2.w);
        sXY[tid] = hxy;
        sZ2[tid] = hz;

        if (tid < TBL) {
            const float r = (float)tid * (0.5f / (float)(TBL - 1));
            float acc = 0.f;
            #pragma unroll
            for (int kk = 0; kk < HI; ++kk) {
                const float s = __expf(-2.0f * fmaf(r, Wi1[kk], bi1[kk]));
                const float den = 1.0f + s;
                acc += 4.0f * Wi1[kk] * Wi2[kk] * s *
                       __builtin_amdgcn_rcpf(den * den);
            }
            sT[tid] = acc;
        }
    }
    __syncthreads();

    const int lane = tid & 63;
    const int wid  = tid >> 6;
    const int i    = blockIdx.x * IPB + wid;

    const float zix = z[3 * i + 0];
    const float ziy = z[3 * i + 1];
    const float ziz = z[3 * i + 2];

    // ---- f_net MLP: lane = hidden unit (cheap tanh) ----
    float v0, v1, v2, grow;
    {
        const float tval = t_in[0];
        float pre = zix * W1[0 * HID + lane]
                  + ziy * W1[1 * HID + lane]
                  + ziz * W1[2 * HID + lane]
                  + tval * W1[3 * HID + lane]
                  + b1[lane];
        const float e2 = __expf(2.0f * pre);
        const float h = 1.0f - 2.0f * __builtin_amdgcn_rcpf(e2 + 1.0f);
        float pv0 = h * Wv[lane * 3 + 0];
        float pv1 = h * Wv[lane * 3 + 1];
        float pv2 = h * Wv[lane * 3 + 2];
        float pg  = h * Wg[lane];
        #pragma unroll
        for (int s = 1; s < 64; s <<= 1) {
            pv0 += __shfl_xor(pv0, s);
            pv1 += __shfl_xor(pv1, s);
            pv2 += __shfl_xor(pv2, s);
            pg  += __shfl_xor(pg, s);
        }
        v0 = pv0 + bv[0];
        v1 = pv1 + bv[1];
        v2 = pv2 + bv[2];
        grow = pg + bg[0];
    }

    unsigned short* myl = lists[wid];
    int cnt = 0;

    // ---- phase 1: f16 packed scan, 2 LDS ops + one ballot chain per unit ----
    {
        const __half2 hxi = __float2half2_rn(zix);
        const __half2 hyi = __float2half2_rn(ziy);
        const __half2 hzi = __float2half2_rn(ziz);
        for (int tt = 0; tt < NUNIT / 64; ++tt) {        // 16 iters
            const int u = tt * 64 + lane;
            const H2x4 xy = sXY[u];
            const H2x2 zz = sZ2[u];
            const __half2 dxa = __hsub2(hxi, xy.xa);
            const __half2 dya = __hsub2(hyi, xy.ya);
            const __half2 dza = __hsub2(hzi, zz.a);
            const __half2 dxb = __hsub2(hxi, xy.xb);
            const __half2 dyb = __hsub2(hyi, xy.yb);
            const __half2 dzb = __hsub2(hzi, zz.b);
            const __half2 d2a = __hfma2(dxa, dxa, __hfma2(dya, dya, __hmul2(dza, dza)));
            const __half2 d2b = __hfma2(dxb, dxb, __hfma2(dyb, dyb, __hmul2(dzb, dzb)));
            const float m0 = __low2float(d2a), m1 = __high2float(d2a);
            const float m2 = __low2float(d2b), m3 = __high2float(d2b);
            const float m = fminf(fminf(m0, m1), fminf(m2, m3));
            const bool pred = (m < SCAN_THR);
            const unsigned long long bal = __ballot(pred);
            const unsigned int lo = (unsigned int)bal, hi = (unsigned int)(bal >> 32);
            const int pre = __builtin_amdgcn_mbcnt_hi(hi, __builtin_amdgcn_mbcnt_lo(lo, 0u));
            if (pred) myl[cnt + pre] = (unsigned short)u;
            cnt += __popcll(bal);
        }
    }

    // ---- phase 2: process flagged units; exact f32 from global (L2), table dU ----
    float fx = 0.f, fy = 0.f, fz = 0.f;
    {
        const float4* z4 = (const float4*)z;
        const float4* l4 = (const float4*)lnw;
        for (int base = 0; base < cnt; base += 64) {
            const int k = base + lane;
            const bool valid = (k < cnt);
            const int e = valid ? (int)myl[k] : 0;
            const float4 r0 = z4[3 * e + 0];
            const float4 r1 = z4[3 * e + 1];
            const float4 r2 = z4[3 * e + 2];
            const float4 lw = l4[e];
            #pragma unroll
            for (int q = 0; q < 4; ++q) {
                const int j = 4 * e + q;
                const float xj = (q == 0) ? r0.x : (q == 1) ? r0.w : (q == 2) ? r1.z : r2.y;
                const float yj = (q == 0) ? r0.y : (q == 1) ? r1.x : (q == 2) ? r1.w : r2.z;
                const float zj = (q == 0) ? r0.z : (q == 1) ? r1.y : (q == 2) ? r2.x : r2.w;
                const float lj = (q == 0) ? lw.x : (q == 1) ? lw.y : (q == 2) ? lw.z : lw.w;
                const float dx = zix - xj;
                const float dy = ziy - yj;
                const float dz = ziz - zj;
                const float d2 = dx * dx + dy * dy + dz * dz + 1e-8f;
                const float r = __builtin_amdgcn_sqrtf(d2);
                const bool ok = valid && (r < 0.5f) && (j != i);
                const float u = r * TSCALE;
                int i0 = (int)u;
                i0 = i0 > (TBL - 2) ? (TBL - 2) : i0;
                const float fr = u - (float)i0;
                const float t0 = sT[i0], t1 = sT[i0 + 1];
                const float dU = fmaf(fr, t1 - t0, t0);
                const float wj = __expf(lj);
                const float coeff = ok
                    ? (-0.0625f) * wj * dU * __builtin_amdgcn_rcpf(r) : 0.0f;
                fx = fmaf(coeff, dx, fx);
                fy = fmaf(coeff, dy, fy);
                fz = fmaf(coeff, dz, fz);
            }
        }
    }

    #pragma unroll
    for (int s = 1; s < 64; s <<= 1) {
        fx += __shfl_xor(fx, s);
        fy += __shfl_xor(fy, s);
        fz += __shfl_xor(fz, s);
    }

    if (lane == 0) {
        out[i * 3 + 0] = v0 + fx;
        out[i * 3 + 1] = v1 + fy;
        out[i * 3 + 2] = v2 + fz;
        out[NPART * 3 + i] = grow;                         // dlnw_dt
        const float wi = __expf(lnw[i]);
        out[NPART * 3 + NPART + i] =
            (v0 * v0 + v1 * v1 + v2 * v2 + grow * grow) * wi;  // dm_dt
    }
}

extern "C" void kernel_launch(void* const* d_in, const int* in_sizes, int n_in,
                              void* d_out, int out_size, void* d_ws, size_t ws_size,
                              hipStream_t stream) {
    const float* t_in = (const float*)d_in[0];
    const float* z    = (const float*)d_in[1];
    const float* lnw  = (const float*)d_in[2];
    const float* W1   = (const float*)d_in[3];
    const float* b1   = (const float*)d_in[4];
    const float* Wv   = (const float*)d_in[5];
    const float* bv   = (const float*)d_in[6];
    const float* Wg   = (const float*)d_in[7];
    const float* bg   = (const float*)d_in[8];
    const float* Wi1  = (const float*)d_in[9];
    const float* bi1  = (const float*)d_in[10];
    const float* Wi2  = (const float*)d_in[11];
    const float* bi2  = (const float*)d_in[12];
    (void)bi2;
    float* out = (float*)d_out;

    odefunc_kernel<<<dim3(NPART / IPB), dim3(BLOCK), 0, stream>>>(
        t_in, z, lnw, W1, b1, Wv, bv, Wg, bg, Wi1, bi1, Wi2, bi2, out);
}

// Round 15
// 13.244 us; speedup vs baseline: 1.0810x; 1.0137x over previous
//
#include <hip/hip_runtime.h>
#include <hip/hip_fp16.h>
#include <math.h>

#define NPART 4096
#define HID 64
#define HI 8
#define IPB 16                  // particles per block = waves per block
#define BLOCK (IPB * 64)        // 1024 threads
#define NUNIT (NPART / 4)       // 1024 scan units of 4 particles
#define CAP 256                 // per-wave flagged-unit list (lambda~52, max~130)
#define TBL 256                 // dU(r) table, r in [0, 0.5]
#define TSCALE ((float)(TBL - 1) / 0.5f)
#define SCAN_THR 0.26f          // covers f16 rounding; process rechecks exact f32

struct alignas(16) H2x4 { __half2 xa, xb, ya, yb; };  // x,y of one 4-particle unit (b128)
struct alignas(8)  H2x2 { __half2 a, b; };            // z of one unit (b64)

// ---- DPP wave-sum: pure VALU (no DS pipe), total lands in lane 63 ----
template<int CTRL, int ROW_MASK, int BANK_MASK>
__device__ __forceinline__ float dpp_add(float v) {
    const int s = __builtin_amdgcn_update_dpp(
        0, __float_as_int(v), CTRL, ROW_MASK, BANK_MASK, true);
    return v + __int_as_float(s);
}
__device__ __forceinline__ float wave_sum63(float v) {
    v = dpp_add<0x111, 0xF, 0xF>(v);   // row_shr:1
    v = dpp_add<0x112, 0xF, 0xF>(v);   // row_shr:2
    v = dpp_add<0x114, 0xF, 0xE>(v);   // row_shr:4  bank_mask 0xe
    v = dpp_add<0x118, 0xF, 0xC>(v);   // row_shr:8  bank_mask 0xc
    v = dpp_add<0x142, 0xA, 0xF>(v);   // row_bcast:15 row_mask 0xa
    v = dpp_add<0x143, 0xC, 0xF>(v);   // row_bcast:31 row_mask 0xc
    return v;                          // lane 63 = full 64-lane sum
}

__global__ __launch_bounds__(BLOCK) void odefunc_kernel(
    const float* __restrict__ t_in,
    const float* __restrict__ z,
    const float* __restrict__ lnw,
    const float* __restrict__ W1,
    const float* __restrict__ b1,
    const float* __restrict__ Wv,
    const float* __restrict__ bv,
    const float* __restrict__ Wg,
    const float* __restrict__ bg,
    const float* __restrict__ Wi1,
    const float* __restrict__ bi1,
    const float* __restrict__ Wi2,
    const float* __restrict__ bi2,
    float* __restrict__ out)
{
    __shared__ H2x4 sXY[NUNIT];                 // 16 KB
    __shared__ H2x2 sZ2[NUNIT];                 //  8 KB
    __shared__ float2 sT2[TBL];                 //  2 KB  (value, delta)
    __shared__ unsigned short lists[IPB][CAP];  //  8 KB

    const int tid = threadIdx.x;

    // ---- prologue: one unit (4 particles) per thread -> f16 SoA; dU table ----
    {
        const float4* z4 = (const float4*)z;
        const float4 r0 = z4[3 * tid + 0];
        const float4 r1 = z4[3 * tid + 1];
        const float4 r2 = z4[3 * tid + 2];
        // particle q of unit tid: q0=(r0.x,r0.y,r0.z) q1=(r0.w,r1.x,r1.y)
        //                         q2=(r1.z,r1.w,r2.x) q3=(r2.y,r2.z,r2.w)
        H2x4 hxy;
        hxy.xa = __floats2half2_rn(r0.x, r0.w);
        hxy.xb = __floats2half2_rn(r1.z, r2.y);
        hxy.ya = __floats2half2_rn(r0.y, r1.x);
        hxy.yb = __floats2half2_rn(r1.w, r2.z);
        H2x2 hz;
        hz.a = __floats2half2_rn(r0.z, r1.y);
        hz.b = __floats2half2_rn(r2.x, r2.w);
        sXY[tid] = hxy;
        sZ2[tid] = hz;

        if (tid < TBL) {
            float accs[2];
            #pragma unroll
            for (int m = 0; m < 2; ++m) {
                const float r = (float)(tid + m) * (0.5f / (float)(TBL - 1));
                float acc = 0.f;
                #pragma unroll
                for (int kk = 0; kk < HI; ++kk) {
                    const float s = __expf(-2.0f * fmaf(r, Wi1[kk], bi1[kk]));
                    const float den = 1.0f + s;
                    acc += 4.0f * Wi1[kk] * Wi2[kk] * s *
                           __builtin_amdgcn_rcpf(den * den);
                }
                accs[m] = acc;
            }
            sT2[tid] = make_float2(accs[0], accs[1] - accs[0]);
        }
    }
    __syncthreads();

    const int lane = tid & 63;
    const int wid  = tid >> 6;
    const int i    = blockIdx.x * IPB + wid;

    const float zix = z[3 * i + 0];
    const float ziy = z[3 * i + 1];
    const float ziz = z[3 * i + 2];

    // ---- f_net MLP: lane = hidden unit; DPP reductions (totals in lane 63) ----
    float v0, v1, v2, grow;
    {
        const float tval = t_in[0];
        float pre = zix * W1[0 * HID + lane]
                  + ziy * W1[1 * HID + lane]
                  + ziz * W1[2 * HID + lane]
                  + tval * W1[3 * HID + lane]
                  + b1[lane];
        const float e2 = __expf(2.0f * pre);
        const float h = 1.0f - 2.0f * __builtin_amdgcn_rcpf(e2 + 1.0f);
        v0   = wave_sum63(h * Wv[lane * 3 + 0]) + bv[0];
        v1   = wave_sum63(h * Wv[lane * 3 + 1]) + bv[1];
        v2   = wave_sum63(h * Wv[lane * 3 + 2]) + bv[2];
        grow = wave_sum63(h * Wg[lane]) + bg[0];
    }

    unsigned short* myl = lists[wid];
    int cnt = 0;

    // ---- phase 1: f16 packed scan, 2 LDS ops + one ballot chain per unit ----
    {
        const __half2 hxi = __float2half2_rn(zix);
        const __half2 hyi = __float2half2_rn(ziy);
        const __half2 hzi = __float2half2_rn(ziz);
        for (int tt = 0; tt < NUNIT / 64; ++tt) {        // 16 iters
            const int u = tt * 64 + lane;
            const H2x4 xy = sXY[u];
            const H2x2 zz = sZ2[u];
            const __half2 dxa = __hsub2(hxi, xy.xa);
            const __half2 dya = __hsub2(hyi, xy.ya);
            const __half2 dza = __hsub2(hzi, zz.a);
            const __half2 dxb = __hsub2(hxi, xy.xb);
            const __half2 dyb = __hsub2(hyi, xy.yb);
            const __half2 dzb = __hsub2(hzi, zz.b);
            const __half2 d2a = __hfma2(dxa, dxa, __hfma2(dya, dya, __hmul2(dza, dza)));
            const __half2 d2b = __hfma2(dxb, dxb, __hfma2(dyb, dyb, __hmul2(dzb, dzb)));
            const float m0 = __low2float(d2a), m1 = __high2float(d2a);
            const float m2 = __low2float(d2b), m3 = __high2float(d2b);
            const float m = fminf(fminf(m0, m1), fminf(m2, m3));
            const bool pred = (m < SCAN_THR);
            const unsigned long long bal = __ballot(pred);
            const unsigned int lo = (unsigned int)bal, hi = (unsigned int)(bal >> 32);
            const int pre = __builtin_amdgcn_mbcnt_hi(hi, __builtin_amdgcn_mbcnt_lo(lo, 0u));
            if (pred) myl[cnt + pre] = (unsigned short)u;
            cnt += __popcll(bal);
        }
    }

    // ---- phase 2: process flagged units; exact f32 from global (L2), table dU ----
    float fx = 0.f, fy = 0.f, fz = 0.f;
    {
        const float4* z4 = (const float4*)z;
        const float4* l4 = (const float4*)lnw;
        for (int base = 0; base < cnt; base += 64) {
            const int k = base + lane;
            const bool valid = (k < cnt);
            const int e = valid ? (int)myl[k] : 0;
            const float4 r0 = z4[3 * e + 0];
            const float4 r1 = z4[3 * e + 1];
            const float4 r2 = z4[3 * e + 2];
            const float4 lw = l4[e];
            #pragma unroll
            for (int q = 0; q < 4; ++q) {
                const int j = 4 * e + q;
                const float xj = (q == 0) ? r0.x : (q == 1) ? r0.w : (q == 2) ? r1.z : r2.y;
                const float yj = (q == 0) ? r0.y : (q == 1) ? r1.x : (q == 2) ? r1.w : r2.z;
                const float zj = (q == 0) ? r0.z : (q == 1) ? r1.y : (q == 2) ? r2.x : r2.w;
                const float lj = (q == 0) ? lw.x : (q == 1) ? lw.y : (q == 2) ? lw.z : lw.w;
                const float dx = zix - xj;
                const float dy = ziy - yj;
                const float dz = ziz - zj;
                const float d2 = dx * dx + dy * dy + dz * dz + 1e-8f;
                const float r = __builtin_amdgcn_sqrtf(d2);
                const bool ok = valid && (r < 0.5f) && (j != i);
                const float u = r * TSCALE;
                int i0 = (int)u;
                i0 = i0 > (TBL - 2) ? (TBL - 2) : i0;
                const float fr = u - (float)i0;
                const float2 tv = sT2[i0];               // one b64: (value, delta)
                const float dU = fmaf(fr, tv.y, tv.x);
                const float wj = __expf(lj);
                const float coeff = ok
                    ? (-0.0625f) * wj * dU * __builtin_amdgcn_rcpf(r) : 0.0f;
                fx = fmaf(coeff, dx, fx);
                fy = fmaf(coeff, dy, fy);
                fz = fmaf(coeff, dz, fz);
            }
        }
    }

    // ---- force reduction via DPP (totals in lane 63) ----
    fx = wave_sum63(fx);
    fy = wave_sum63(fy);
    fz = wave_sum63(fz);

    if (lane == 63) {
        out[i * 3 + 0] = v0 + fx;
        out[i * 3 + 1] = v1 + fy;
        out[i * 3 + 2] = v2 + fz;
        out[NPART * 3 + i] = grow;                         // dlnw_dt
        const float wi = __expf(lnw[i]);
        out[NPART * 3 + NPART + i] =
            (v0 * v0 + v1 * v1 + v2 * v2 + grow * grow) * wi;  // dm_dt
    }
}

extern "C" void kernel_launch(void* const* d_in, const int* in_sizes, int n_in,
                              void* d_out, int out_size, void* d_ws, size_t ws_size,
                              hipStream_t stream) {
    const float* t_in = (const float*)d_in[0];
    const float* z    = (const float*)d_in[1];
    const float* lnw  = (const float*)d_in[2];
    const float* W1   = (const float*)d_in[3];
    const float* b1   = (const float*)d_in[4];
    const float* Wv   = (const float*)d_in[5];
    const float* bv   = (const float*)d_in[6];
    const float* Wg   = (const float*)d_in[7];
    const float* bg   = (const float*)d_in[8];
    const float* Wi1  = (const float*)d_in[9];
    const float* bi1  = (const float*)d_in[10];
    const float* Wi2  = (const float*)d_in[11];
    const float* bi2  = (const float*)d_in[12];
    (void)bi2;
    float* out = (float*)d_out;

    odefunc_kernel<<<dim3(NPART / IPB), dim3(BLOCK), 0, stream>>>(
        t_in, z, lnw, W1, b1, Wv, bv, Wg, bg, Wi1, bi1, Wi2, bi2, out);
}